// Round 14
// baseline (308.255 us; speedup 1.0000x reference)
//
#include <hip/hip_runtime.h>
#include <hip/hip_bf16.h>

#define RES 512
#define NC 16
#define NPLANES 3
#define NB 32
#define NCELLS (NB * NB * NB)   // 32768 = 128 * 256

typedef float f32x4 __attribute__((ext_vector_type(4)));

static __device__ inline float nt_loadf(const float* p) { return __builtin_nontemporal_load(p); }
static __device__ inline f32x4 nt_load4(const float* p) {
  return __builtin_nontemporal_load((const f32x4*)p);
}
static __device__ inline unsigned nt_loadu(const unsigned* p) { return __builtin_nontemporal_load(p); }
static __device__ inline void nt_store4(float* p, f32x4 v) {
  __builtin_nontemporal_store(v, (f32x4*)p);
}
static __device__ inline float bf_lo(unsigned u) { return __uint_as_float(u << 16); }
static __device__ inline float bf_hi(unsigned u) { return __uint_as_float(u & 0xFFFF0000u); }

#define NORM_K ((float)(2.0 / (-2.0 * 1.3)))

// ---------------------------------------------------------------------------
// Transpose planes [3][16][512][512] f32 -> [3][512][512][16] bf16
// ---------------------------------------------------------------------------
__global__ __launch_bounds__(256) void transpose_planes_k(
    const float* __restrict__ in, __hip_bfloat16* __restrict__ out)
{
  __shared__ float sm[NC][64 + 1];
  int b   = blockIdx.x;
  int xb  = b & 7;
  int y   = (b >> 3) & 511;
  int p   = b >> 12;
  int x0  = xb << 6;
  int tid = threadIdx.x;
#pragma unroll
  for (int k = 0; k < 4; ++k) {
    int e = tid + k * 256;
    int c = e >> 6, x = e & 63;
    sm[c][x] = nt_loadf(&in[(size_t)((p * NC + c) * RES + y) * RES + x0 + x]);
  }
  __syncthreads();
#pragma unroll
  for (int k = 0; k < 4; ++k) {
    int e = tid + k * 256;
    int x = e >> 4, c = e & 15;
    out[(size_t)((p * RES + y) * RES + x0 + x) * NC + c] = __float2bfloat16(sm[c][x]);
  }
}

__global__ void transpose_lines_k(const float* __restrict__ in, float* __restrict__ out)
{
  int i = blockIdx.x * 256 + threadIdx.x;
  if (i >= NPLANES * RES * NC) return;
  int c = i & 15;
  int l = (i >> 4) & 511;
  int p = i >> 13;
  out[i] = nt_loadf(&in[(p * NC + c) * RES + l]);
}

// ---------------------------------------------------------------------------
// Counting sort: zero -> hist+rank (one atomic pass) -> 2-stage scan ->
// atomic-free scatter (scan stage-3 fused into scatter's offs lookup).
// ---------------------------------------------------------------------------
static __device__ inline int cell_of(float px, float py, float pz)
{
  float n0 = (px - 1.3f) * NORM_K - 1.0f;
  float n1 = (py - 1.3f) * NORM_K - 1.0f;
  float n2 = (pz - 1.3f) * NORM_K - 1.0f;
  int cx = (int)((n0 + 1.0f) * 16.0f); cx = cx < 0 ? 0 : (cx > NB - 1 ? NB - 1 : cx);
  int cy = (int)((n1 + 1.0f) * 16.0f); cy = cy < 0 ? 0 : (cy > NB - 1 ? NB - 1 : cy);
  int cz = (int)((n2 + 1.0f) * 16.0f); cz = cz < 0 ? 0 : (cz > NB - 1 ? NB - 1 : cz);
  return (cx << 10) | (cy << 5) | cz;   // cz fastest: XY-tile reuse across cz
}

__global__ void zero_hist_k(unsigned* __restrict__ hist)
{
  int i = blockIdx.x * 256 + threadIdx.x;
  if (i < NCELLS) hist[i] = 0;
}

__global__ __launch_bounds__(256) void histrank_k(
    const float* __restrict__ pts, unsigned* __restrict__ hist,
    unsigned* __restrict__ rank, int N)
{
  int base = (blockIdx.x * 256 + threadIdx.x) * 4;
  if (base >= N) return;
  if (base + 4 <= N) {
    const f32x4* p4 = (const f32x4*)(pts + 3 * (size_t)base);
    f32x4 a = p4[0], b = p4[1], c = p4[2];
    int c0 = cell_of(a.x, a.y, a.z);
    int c1 = cell_of(a.w, b.x, b.y);
    int c2 = cell_of(b.z, b.w, c.x);
    int c3 = cell_of(c.y, c.z, c.w);
    uint4 rv;
    rv.x = atomicAdd(&hist[c0], 1u);
    rv.y = atomicAdd(&hist[c1], 1u);
    rv.z = atomicAdd(&hist[c2], 1u);
    rv.w = atomicAdd(&hist[c3], 1u);
    *(uint4*)(rank + base) = rv;
  } else {
    for (int j = 0; j < 4 && base + j < N; ++j) {
      int i = base + j;
      int cc = cell_of(pts[3 * i], pts[3 * i + 1], pts[3 * i + 2]);
      rank[i] = atomicAdd(&hist[cc], 1u);
    }
  }
}

__global__ __launch_bounds__(256) void scan1_k(
    const unsigned* __restrict__ hist, unsigned* __restrict__ offs,
    unsigned* __restrict__ bsum)
{
  __shared__ unsigned s[256];
  int b = blockIdx.x, t = threadIdx.x;
  unsigned v = hist[b * 256 + t];
  s[t] = v;
  __syncthreads();
  for (int d = 1; d < 256; d <<= 1) {
    unsigned u = (t >= d) ? s[t - d] : 0u;
    __syncthreads();
    s[t] += u;
    __syncthreads();
  }
  offs[b * 256 + t] = s[t] - v;   // exclusive within block
  if (t == 255) bsum[b] = s[255];
}

__global__ __launch_bounds__(128) void scan2_k(unsigned* __restrict__ bsum)
{
  __shared__ unsigned s[128];
  int t = threadIdx.x;
  unsigned v = bsum[t];
  s[t] = v;
  __syncthreads();
  for (int d = 1; d < 128; d <<= 1) {
    unsigned u = (t >= d) ? s[t - d] : 0u;
    __syncthreads();
    s[t] += u;
    __syncthreads();
  }
  bsum[t] = s[t] - v;   // exclusive
}

// Atomic-free scatter; global off = offs[cell] + bsum[cell>>8] (scan3 fused).
__global__ __launch_bounds__(256) void scatter_k(
    const float* __restrict__ pts, const float* __restrict__ ts,
    const unsigned* __restrict__ rank, const unsigned* __restrict__ offs,
    const unsigned* __restrict__ bsum,
    f32x4* __restrict__ rec, unsigned* __restrict__ oidx, int N)
{
  int base = (blockIdx.x * 256 + threadIdx.x) * 4;
  if (base >= N) return;
  if (base + 4 <= N) {
    uint4 rv = *(const uint4*)(rank + base);
    const f32x4* p4 = (const f32x4*)(pts + 3 * (size_t)base);
    f32x4 a = p4[0], b = p4[1], c = p4[2];
    f32x4 tv = *(const f32x4*)(ts + base);
    int c0 = cell_of(a.x, a.y, a.z);
    int c1 = cell_of(a.w, b.x, b.y);
    int c2 = cell_of(b.z, b.w, c.x);
    int c3 = cell_of(c.y, c.z, c.w);
    unsigned p0 = offs[c0] + bsum[c0 >> 8] + rv.x;
    unsigned p1 = offs[c1] + bsum[c1 >> 8] + rv.y;
    unsigned p2 = offs[c2] + bsum[c2 >> 8] + rv.z;
    unsigned p3 = offs[c3] + bsum[c3 >> 8] + rv.w;
    f32x4 r0; r0.x = a.x; r0.y = a.y; r0.z = a.z; r0.w = tv.x;
    f32x4 r1; r1.x = a.w; r1.y = b.x; r1.z = b.y; r1.w = tv.y;
    f32x4 r2; r2.x = b.z; r2.y = b.w; r2.z = c.x; r2.w = tv.z;
    f32x4 r3; r3.x = c.y; r3.y = c.z; r3.z = c.w; r3.w = tv.w;
    rec[p0] = r0; rec[p1] = r1; rec[p2] = r2; rec[p3] = r3;
    oidx[p0] = base + 0; oidx[p1] = base + 1;
    oidx[p2] = base + 2; oidx[p3] = base + 3;
  } else {
    for (int j = 0; j < 4 && base + j < N; ++j) {
      int i = base + j;
      int cc = cell_of(pts[3 * i], pts[3 * i + 1], pts[3 * i + 2]);
      unsigned pos = offs[cc] + bsum[cc >> 8] + rank[i];
      f32x4 r; r.x = pts[3 * i]; r.y = pts[3 * i + 1]; r.z = pts[3 * i + 2];
      r.w = ts[i];
      rec[pos] = r;
      oidx[pos] = i;
    }
  }
}

// ---------------------------------------------------------------------------
// Sorted main kernel. NEW vs R13: per-plane loads are BATCHED — all 8 texel
// uint4 + 8 line float4 issued into named registers before any compute, so
// each wave keeps ~16 gathers in flight (R12's VGPR=56 showed the compiler
// was dribbling 2-3 loads at a time -> latency-bound at 3.4 TB/s).
// rec/oidx read nontemporal (read-once streams; keep L3 for planes).
// Output: two 16-output phases, wave-coop full-64B-line scattered stores.
// ---------------------------------------------------------------------------
__global__ __launch_bounds__(256) void visnerf_sorted_k(
    const f32x4* __restrict__ rec, const unsigned* __restrict__ oidx,
    const __hip_bfloat16* __restrict__ planesb, const float* __restrict__ lines,
    const float* __restrict__ pg, const float* __restrict__ W,
    float* __restrict__ out, int N)
{
  __shared__ __align__(16) float sW[32 * 20];
  __shared__ __align__(16) float st[256 * 16];
  __shared__ float spg[9];
  int tid = threadIdx.x;
  for (int e = tid; e < 640; e += 256) {
    int o = e / 20, c = e - o * 20;
    sW[e] = (c < 19) ? W[o * 19 + c] : 0.0f;
  }
  if (tid < 9) spg[tid] = pg[tid];
  __syncthreads();

  int nwg = gridDim.x, bid = blockIdx.x;
  int sbid = ((nwg & 7) == 0) ? ((bid & 7) * (nwg >> 3) + (bid >> 3)) : bid;
  int j  = sbid * 256 + tid;
  int jc = (j < N) ? j : (N - 1);

  f32x4 r = nt_load4((const float*)(rec + jc));
  unsigned oi = nt_loadu(oidx + jc);
  float t = r.w;

  float nn[3];
  nn[0] = (r.x - 1.3f) * NORM_K - 1.0f;
  nn[1] = (r.y - 1.3f) * NORM_K - 1.0f;
  nn[2] = (r.z - 1.3f) * NORM_K - 1.0f;

  float feats[20];
#pragma unroll
  for (int c = 0; c < 20; ++c) feats[c] = 0.0f;

  const int matx[3] = {0, 0, 1};
  const int maty[3] = {1, 2, 2};
  const int vecm[3] = {2, 1, 0};

#pragma unroll
  for (int q = 0; q < 3; ++q) {
    float x  = nn[matx[q]], y = nn[maty[q]], lc = nn[vecm[q]];
    float ix = (x + 1.0f) * 0.5f * (float)(RES - 1);
    float iy = (y + 1.0f) * 0.5f * (float)(RES - 1);
    float fx = floorf(ix), fy = floorf(iy);
    float wx = ix - fx, wy = iy - fy;
    int x0 = (int)fx; x0 = x0 < 0 ? 0 : (x0 > RES - 1 ? RES - 1 : x0);
    int y0 = (int)fy; y0 = y0 < 0 ? 0 : (y0 > RES - 1 ? RES - 1 : y0);
    int x1 = (x0 + 1 > RES - 1) ? RES - 1 : x0 + 1;
    int y1 = (y0 + 1 > RES - 1) ? RES - 1 : y0 + 1;

    float il = (lc + 1.0f) * 0.5f * (float)(RES - 1);
    float fl = floorf(il);
    float wl = il - fl;
    int l0 = (int)fl; l0 = l0 < 0 ? 0 : (l0 > RES - 1 ? RES - 1 : l0);
    int l1 = (l0 + 1 > RES - 1) ? RES - 1 : l0 + 1;

    float w00 = (1.0f - wy) * (1.0f - wx);
    float w01 = (1.0f - wy) * wx;
    float w10 = wy * (1.0f - wx);
    float w11 = wy * wx;
    float wl0 = 1.0f - wl;

    const uint4* ta = (const uint4*)(planesb + (size_t)((q * RES + y0) * RES + x0) * NC);
    const uint4* tb = (const uint4*)(planesb + (size_t)((q * RES + y0) * RES + x1) * NC);
    const uint4* tc = (const uint4*)(planesb + (size_t)((q * RES + y1) * RES + x0) * NC);
    const uint4* td = (const uint4*)(planesb + (size_t)((q * RES + y1) * RES + x1) * NC);
    const float4* L0 = (const float4*)(lines + (size_t)(q * RES + l0) * NC);
    const float4* L1 = (const float4*)(lines + (size_t)(q * RES + l1) * NC);

    // BATCH: issue all 16 loads for this plane before any compute.
    uint4 A0 = ta[0], A1 = ta[1];
    uint4 B0 = tb[0], B1 = tb[1];
    uint4 C0 = tc[0], C1 = tc[1];
    uint4 D0 = td[0], D1 = td[1];
    float4 E00 = L0[0], E01 = L0[1], E02 = L0[2], E03 = L0[3];
    float4 E10 = L1[0], E11 = L1[1], E12 = L1[2], E13 = L1[3];

    unsigned pa[8] = {A0.x, A0.y, A0.z, A0.w, A1.x, A1.y, A1.z, A1.w};
    unsigned pb[8] = {B0.x, B0.y, B0.z, B0.w, B1.x, B1.y, B1.z, B1.w};
    unsigned pc[8] = {C0.x, C0.y, C0.z, C0.w, C1.x, C1.y, C1.z, C1.w};
    unsigned pd[8] = {D0.x, D0.y, D0.z, D0.w, D1.x, D1.y, D1.z, D1.w};
    float l0v[16] = {E00.x, E00.y, E00.z, E00.w, E01.x, E01.y, E01.z, E01.w,
                     E02.x, E02.y, E02.z, E02.w, E03.x, E03.y, E03.z, E03.w};
    float l1v[16] = {E10.x, E10.y, E10.z, E10.w, E11.x, E11.y, E11.z, E11.w,
                     E12.x, E12.y, E12.z, E12.w, E13.x, E13.y, E13.z, E13.w};

#pragma unroll
    for (int w = 0; w < 8; ++w) {
      int c0 = 2 * w;
      float pf0 = w00 * bf_lo(pa[w]) + w01 * bf_lo(pb[w]) +
                  w10 * bf_lo(pc[w]) + w11 * bf_lo(pd[w]);
      float pf1 = w00 * bf_hi(pa[w]) + w01 * bf_hi(pb[w]) +
                  w10 * bf_hi(pc[w]) + w11 * bf_hi(pd[w]);
      float lf0 = wl0 * l0v[2 * w]     + wl * l1v[2 * w];
      float lf1 = wl0 * l0v[2 * w + 1] + wl * l1v[2 * w + 1];
      feats[c0 + 0] += pf0 * lf0;
      feats[c0 + 1] += pf1 * lf1;
    }
  }

  {
    float it = (t + 1.0f) * 0.5f * 2.0f;
    float ft = floorf(it);
    float wt = it - ft;
    int t0 = (int)ft; t0 = t0 < 0 ? 0 : (t0 > 2 ? 2 : t0);
    int t1 = (t0 + 1 > 2) ? 2 : t0 + 1;
    feats[16] = spg[0 + t0] * (1.0f - wt) + spg[0 + t1] * wt;
    feats[17] = spg[3 + t0] * (1.0f - wt) + spg[3 + t1] * wt;
    feats[18] = spg[6 + t0] * (1.0f - wt) + spg[6 + t1] * wt;
    feats[19] = 0.0f;
  }

  int lane  = tid & 63;
  int wbase = tid & ~63;
  int chunk = lane & 3;
  int psel  = lane >> 2;
#pragma unroll
  for (int ph = 0; ph < 2; ++ph) {
#pragma unroll
    for (int o = 0; o < 16; ++o) {
      int oo = ph * 16 + o;
      const float4* wr = (const float4*)(sW + oo * 20);
      float acc = 0.0f;
#pragma unroll
      for (int k = 0; k < 5; ++k) {
        float4 wv = wr[k];
        acc += feats[4 * k + 0] * wv.x + feats[4 * k + 1] * wv.y +
               feats[4 * k + 2] * wv.z + feats[4 * k + 3] * wv.w;
      }
      st[tid * 16 + ((o + (tid >> 1)) & 15)] = acc;
    }
#pragma unroll
    for (int g = 0; g < 4; ++g) {
      int owner_lane = g * 16 + psel;
      int pt = wbase + owner_lane;
      int jp = sbid * 256 + pt;
      unsigned oi_p = (unsigned)__shfl((int)oi, owner_lane, 64);
      f32x4 v;
#pragma unroll
      for (int jj = 0; jj < 4; ++jj) {
        int o = chunk * 4 + jj;
        v[jj] = st[pt * 16 + ((o + (pt >> 1)) & 15)];
      }
      if (jp < N) nt_store4(out + (size_t)oi_p * 32 + ph * 16 + chunk * 4, v);
    }
  }
}

// ---------------------------------------------------------------------------
// R6 fallback main kernel (unsorted), for small-ws case.
// ---------------------------------------------------------------------------
template <bool TP>
__global__ __launch_bounds__(256) void visnerf_main_k(
    const float* __restrict__ pts, const float* __restrict__ ts,
    const __hip_bfloat16* __restrict__ planesb, const float* __restrict__ lines,
    const float* __restrict__ planes_f32, const float* __restrict__ lines_f32,
    const float* __restrict__ pg, const float* __restrict__ W,
    float* __restrict__ out, int N)
{
  __shared__ __align__(16) float sW[32 * 20];
  __shared__ __align__(16) float st[256 * 32];
  __shared__ float spg[9];
  int tid = threadIdx.x;
  for (int e = tid; e < 640; e += 256) {
    int o = e / 20, c = e - o * 20;
    sW[e] = (c < 19) ? W[o * 19 + c] : 0.0f;
  }
  if (tid < 9) spg[tid] = pg[tid];
  __syncthreads();

  int i  = blockIdx.x * 256 + tid;
  int ii = (i < N) ? i : (N - 1);
  float px = nt_loadf(&pts[ii * 3 + 0]);
  float py = nt_loadf(&pts[ii * 3 + 1]);
  float pz = nt_loadf(&pts[ii * 3 + 2]);
  float t  = nt_loadf(&ts[ii]);

  float nn[3];
  nn[0] = (px - 1.3f) * NORM_K - 1.0f;
  nn[1] = (py - 1.3f) * NORM_K - 1.0f;
  nn[2] = (pz - 1.3f) * NORM_K - 1.0f;

  float feats[20];
#pragma unroll
  for (int c = 0; c < 20; ++c) feats[c] = 0.0f;

  const int matx[3] = {0, 0, 1};
  const int maty[3] = {1, 2, 2};
  const int vecm[3] = {2, 1, 0};

#pragma unroll
  for (int q = 0; q < 3; ++q) {
    float x  = nn[matx[q]], y = nn[maty[q]], lc = nn[vecm[q]];
    float ix = (x + 1.0f) * 0.5f * (float)(RES - 1);
    float iy = (y + 1.0f) * 0.5f * (float)(RES - 1);
    float fx = floorf(ix), fy = floorf(iy);
    float wx = ix - fx, wy = iy - fy;
    int x0 = (int)fx; x0 = x0 < 0 ? 0 : (x0 > RES - 1 ? RES - 1 : x0);
    int y0 = (int)fy; y0 = y0 < 0 ? 0 : (y0 > RES - 1 ? RES - 1 : y0);
    int x1 = (x0 + 1 > RES - 1) ? RES - 1 : x0 + 1;
    int y1 = (y0 + 1 > RES - 1) ? RES - 1 : y0 + 1;

    float il = (lc + 1.0f) * 0.5f * (float)(RES - 1);
    float fl = floorf(il);
    float wl = il - fl;
    int l0 = (int)fl; l0 = l0 < 0 ? 0 : (l0 > RES - 1 ? RES - 1 : l0);
    int l1 = (l0 + 1 > RES - 1) ? RES - 1 : l0 + 1;

    float w00 = (1.0f - wy) * (1.0f - wx);
    float w01 = (1.0f - wy) * wx;
    float w10 = wy * (1.0f - wx);
    float w11 = wy * wx;
    float wl0 = 1.0f - wl;

    if (TP) {
      const uint4* ta = (const uint4*)(planesb + (size_t)((q * RES + y0) * RES + x0) * NC);
      const uint4* tb = (const uint4*)(planesb + (size_t)((q * RES + y0) * RES + x1) * NC);
      const uint4* tc = (const uint4*)(planesb + (size_t)((q * RES + y1) * RES + x0) * NC);
      const uint4* td = (const uint4*)(planesb + (size_t)((q * RES + y1) * RES + x1) * NC);
      const float4* L0 = (const float4*)(lines + (size_t)(q * RES + l0) * NC);
      const float4* L1 = (const float4*)(lines + (size_t)(q * RES + l1) * NC);
#pragma unroll
      for (int h = 0; h < 2; ++h) {
        uint4 ua = ta[h], ub = tb[h], uc = tc[h], ud = td[h];
        float4 e0a = L0[2 * h + 0], e0b = L0[2 * h + 1];
        float4 e1a = L1[2 * h + 0], e1b = L1[2 * h + 1];
        const unsigned* pa = &ua.x;
        const unsigned* pb = &ub.x;
        const unsigned* pc = &uc.x;
        const unsigned* pd = &ud.x;
        const float* q0 = &e0a.x;
        const float* q1 = &e1a.x;
#pragma unroll
        for (int w = 0; w < 4; ++w) {
          int c0 = h * 8 + 2 * w;
          float pf0 = w00 * bf_lo(pa[w]) + w01 * bf_lo(pb[w]) +
                      w10 * bf_lo(pc[w]) + w11 * bf_lo(pd[w]);
          float pf1 = w00 * bf_hi(pa[w]) + w01 * bf_hi(pb[w]) +
                      w10 * bf_hi(pc[w]) + w11 * bf_hi(pd[w]);
          float lf0 = (w < 2) ? (wl0 * q0[2 * w] + wl * q1[2 * w])
                              : (wl0 * (&e0b.x)[2 * w - 4] + wl * (&e1b.x)[2 * w - 4]);
          float lf1 = (w < 2) ? (wl0 * q0[2 * w + 1] + wl * q1[2 * w + 1])
                              : (wl0 * (&e0b.x)[2 * w - 3] + wl * (&e1b.x)[2 * w - 3]);
          feats[c0 + 0] += pf0 * lf0;
          feats[c0 + 1] += pf1 * lf1;
        }
      }
    } else {
#pragma unroll 4
      for (int c = 0; c < NC; ++c) {
        const float* pl = planes_f32 + (size_t)(q * NC + c) * RES * RES;
        float a  = pl[y0 * RES + x0], b = pl[y0 * RES + x1];
        float c2 = pl[y1 * RES + x0], d = pl[y1 * RES + x1];
        const float* ln = lines_f32 + (size_t)(q * NC + c) * RES;
        float lf = ln[l0] * wl0 + ln[l1] * wl;
        feats[c] += (w00 * a + w01 * b + w10 * c2 + w11 * d) * lf;
      }
    }
  }

  {
    float it = (t + 1.0f) * 0.5f * 2.0f;
    float ft = floorf(it);
    float wt = it - ft;
    int t0 = (int)ft; t0 = t0 < 0 ? 0 : (t0 > 2 ? 2 : t0);
    int t1 = (t0 + 1 > 2) ? 2 : t0 + 1;
    feats[16] = spg[0 + t0] * (1.0f - wt) + spg[0 + t1] * wt;
    feats[17] = spg[3 + t0] * (1.0f - wt) + spg[3 + t1] * wt;
    feats[18] = spg[6 + t0] * (1.0f - wt) + spg[6 + t1] * wt;
    feats[19] = 0.0f;
  }

  float res[32];
#pragma unroll
  for (int o = 0; o < 32; ++o) {
    const float4* wr = (const float4*)(sW + o * 20);
    float acc = 0.0f;
#pragma unroll
    for (int k = 0; k < 5; ++k) {
      float4 wv = wr[k];
      acc += feats[4 * k + 0] * wv.x + feats[4 * k + 1] * wv.y +
             feats[4 * k + 2] * wv.z + feats[4 * k + 3] * wv.w;
    }
    res[o] = acc;
  }

#pragma unroll
  for (int o = 0; o < 32; ++o)
    st[tid * 32 + ((o + tid) & 31)] = res[o];
  __syncthreads();

  size_t gbase = (size_t)blockIdx.x * 8192;
  size_t total = (size_t)N * 32;
#pragma unroll
  for (int k = 0; k < 8; ++k) {
    int idx = tid + k * 256;
    int j   = idx * 4;
    int pq  = j >> 5;
    f32x4 v;
    v.x = st[pq * 32 + (((j & 31) + 0 + pq) & 31)];
    v.y = st[pq * 32 + (((j & 31) + 1 + pq) & 31)];
    v.z = st[pq * 32 + (((j & 31) + 2 + pq) & 31)];
    v.w = st[pq * 32 + (((j & 31) + 3 + pq) & 31)];
    if (gbase + j + 4 <= total) {
      nt_store4(out + gbase + j, v);
    }
  }
}

extern "C" void kernel_launch(void* const* d_in, const int* in_sizes, int n_in,
                              void* d_out, int out_size, void* d_ws, size_t ws_size,
                              hipStream_t stream)
{
  const float* pts    = (const float*)d_in[0];
  const float* ts     = (const float*)d_in[1];
  const float* planes = (const float*)d_in[2];
  const float* lines  = (const float*)d_in[3];
  const float* pg     = (const float*)d_in[4];
  const float* W      = (const float*)d_in[5];
  float* out = (float*)d_out;
  int N = in_sizes[0] / 3;
  int blocksN = (N + 255) / 256;
  int blocks4 = (N + 1023) / 1024;

  auto align256 = [](size_t x) { return (x + 255) & ~(size_t)255; };
  size_t planesTb_bytes = align256((size_t)NPLANES * RES * RES * NC * 2);
  size_t linesT_bytes   = align256((size_t)NPLANES * RES * NC * 4);
  size_t hist_bytes     = align256((size_t)NCELLS * 4);
  size_t offs_bytes     = align256((size_t)NCELLS * 4);
  size_t bsum_bytes     = align256((size_t)128 * 4);
  size_t rank_bytes     = align256((size_t)N * 4);
  size_t oidx_bytes     = align256((size_t)N * 4);
  size_t rec_bytes      = align256((size_t)N * 16);
  size_t sorted_total = planesTb_bytes + linesT_bytes + hist_bytes + offs_bytes +
                        bsum_bytes + rank_bytes + oidx_bytes + rec_bytes;

  if (ws_size >= sorted_total) {
    char* p = (char*)d_ws;
    __hip_bfloat16* planesTb = (__hip_bfloat16*)p;       p += planesTb_bytes;
    float*    linesT = (float*)p;                        p += linesT_bytes;
    unsigned* hist   = (unsigned*)p;                     p += hist_bytes;
    unsigned* offs   = (unsigned*)p;                     p += offs_bytes;
    unsigned* bsum   = (unsigned*)p;                     p += bsum_bytes;
    unsigned* rank   = (unsigned*)p;                     p += rank_bytes;
    unsigned* oidx   = (unsigned*)p;                     p += oidx_bytes;
    f32x4*    rec    = (f32x4*)p;

    transpose_planes_k<<<NPLANES * RES * (RES / 64), 256, 0, stream>>>(planes, planesTb);
    transpose_lines_k<<<(NPLANES * RES * NC + 255) / 256, 256, 0, stream>>>(lines, linesT);
    zero_hist_k<<<(NCELLS + 255) / 256, 256, 0, stream>>>(hist);
    histrank_k<<<blocks4, 256, 0, stream>>>(pts, hist, rank, N);
    scan1_k<<<NCELLS / 256, 256, 0, stream>>>(hist, offs, bsum);
    scan2_k<<<1, 128, 0, stream>>>(bsum);
    scatter_k<<<blocks4, 256, 0, stream>>>(pts, ts, rank, offs, bsum, rec, oidx, N);
    visnerf_sorted_k<<<blocksN, 256, 0, stream>>>(rec, oidx, planesTb, linesT,
                                                  pg, W, out, N);
  } else if (ws_size >= planesTb_bytes + linesT_bytes) {
    __hip_bfloat16* planesTb = (__hip_bfloat16*)d_ws;
    float* linesT = (float*)((char*)d_ws + planesTb_bytes);
    transpose_planes_k<<<NPLANES * RES * (RES / 64), 256, 0, stream>>>(planes, planesTb);
    transpose_lines_k<<<(NPLANES * RES * NC + 255) / 256, 256, 0, stream>>>(lines, linesT);
    visnerf_main_k<true><<<blocksN, 256, 0, stream>>>(
        pts, ts, planesTb, linesT, nullptr, nullptr, pg, W, out, N);
  } else {
    visnerf_main_k<false><<<blocksN, 256, 0, stream>>>(
        pts, ts, nullptr, nullptr, planes, lines, pg, W, out, N);
  }
}

// Round 15
// 306.318 us; speedup vs baseline: 1.0063x; 1.0063x over previous
//
#include <hip/hip_runtime.h>
#include <hip/hip_bf16.h>

#define RES 512
#define NC 16
#define NPLANES 3
#define NB 32
#define NCELLS (NB * NB * NB)   // 32768 = 128 * 256

typedef float f32x4 __attribute__((ext_vector_type(4)));

static __device__ inline float nt_loadf(const float* p) { return __builtin_nontemporal_load(p); }
static __device__ inline f32x4 nt_load4(const float* p) {
  return __builtin_nontemporal_load((const f32x4*)p);
}
static __device__ inline unsigned nt_loadu(const unsigned* p) { return __builtin_nontemporal_load(p); }
static __device__ inline void nt_store4(float* p, f32x4 v) {
  __builtin_nontemporal_store(v, (f32x4*)p);
}
static __device__ inline float bf_lo(unsigned u) { return __uint_as_float(u << 16); }
static __device__ inline float bf_hi(unsigned u) { return __uint_as_float(u & 0xFFFF0000u); }

#define NORM_K ((float)(2.0 / (-2.0 * 1.3)))

static __device__ inline int cell_of(float px, float py, float pz)
{
  float n0 = (px - 1.3f) * NORM_K - 1.0f;
  float n1 = (py - 1.3f) * NORM_K - 1.0f;
  float n2 = (pz - 1.3f) * NORM_K - 1.0f;
  int cx = (int)((n0 + 1.0f) * 16.0f); cx = cx < 0 ? 0 : (cx > NB - 1 ? NB - 1 : cx);
  int cy = (int)((n1 + 1.0f) * 16.0f); cy = cy < 0 ? 0 : (cy > NB - 1 ? NB - 1 : cy);
  int cz = (int)((n2 + 1.0f) * 16.0f); cz = cz < 0 ? 0 : (cz > NB - 1 ? NB - 1 : cz);
  return (cx << 10) | (cy << 5) | cz;   // cz fastest: XY-tile reuse across cz
}

// ---------------------------------------------------------------------------
// Fused preprocessing: one dispatch, blockIdx ranges:
//   [0, HB)            histrank (critical path: starts immediately)
//   [HB, HB+96)        transpose lines
//   [HB+96, HB+96+12288) transpose planes f32 -> bf16 channel-innermost
// hist must be zeroed beforehand (hipMemsetAsync on the stream).
// ---------------------------------------------------------------------------
__global__ __launch_bounds__(256) void fused_pre_k(
    const float* __restrict__ planes, __hip_bfloat16* __restrict__ planesTb,
    const float* __restrict__ lines, float* __restrict__ linesT,
    const float* __restrict__ pts, unsigned* __restrict__ hist,
    unsigned* __restrict__ rank, int N, int HB)
{
  int b   = blockIdx.x;
  int tid = threadIdx.x;

  if (b < HB) {
    // ---- histrank: 4 points/thread, one returning atomic per point ----
    int base = (b * 256 + tid) * 4;
    if (base >= N) return;
    if (base + 4 <= N) {
      const f32x4* p4 = (const f32x4*)(pts + 3 * (size_t)base);
      f32x4 a = p4[0], bb = p4[1], c = p4[2];
      int c0 = cell_of(a.x, a.y, a.z);
      int c1 = cell_of(a.w, bb.x, bb.y);
      int c2 = cell_of(bb.z, bb.w, c.x);
      int c3 = cell_of(c.y, c.z, c.w);
      uint4 rv;
      rv.x = atomicAdd(&hist[c0], 1u);
      rv.y = atomicAdd(&hist[c1], 1u);
      rv.z = atomicAdd(&hist[c2], 1u);
      rv.w = atomicAdd(&hist[c3], 1u);
      *(uint4*)(rank + base) = rv;
    } else {
      for (int j = 0; j < 4 && base + j < N; ++j) {
        int i = base + j;
        int cc = cell_of(pts[3 * i], pts[3 * i + 1], pts[3 * i + 2]);
        rank[i] = atomicAdd(&hist[cc], 1u);
      }
    }
    return;
  }
  b -= HB;

  if (b < 96) {
    // ---- transpose lines [3][16][512] -> [3][512][16] ----
    int i = b * 256 + tid;
    int c = i & 15;
    int l = (i >> 4) & 511;
    int p = i >> 13;
    linesT[i] = nt_loadf(&lines[(p * NC + c) * RES + l]);
    return;
  }
  b -= 96;

  // ---- transpose planes: block = p*4096 + y*8 + xb ----
  __shared__ float sm[NC][64 + 1];
  int xb  = b & 7;
  int y   = (b >> 3) & 511;
  int p   = b >> 12;
  int x0  = xb << 6;
#pragma unroll
  for (int k = 0; k < 4; ++k) {
    int e = tid + k * 256;
    int c = e >> 6, x = e & 63;
    sm[c][x] = nt_loadf(&planes[(size_t)((p * NC + c) * RES + y) * RES + x0 + x]);
  }
  __syncthreads();
#pragma unroll
  for (int k = 0; k < 4; ++k) {
    int e = tid + k * 256;
    int x = e >> 4, c = e & 15;
    planesTb[(size_t)((p * RES + y) * RES + x0 + x) * NC + c] = __float2bfloat16(sm[c][x]);
  }
}

// ---------------------------------------------------------------------------
// Standalone transposes for the fallback path.
// ---------------------------------------------------------------------------
__global__ __launch_bounds__(256) void transpose_planes_k(
    const float* __restrict__ in, __hip_bfloat16* __restrict__ out)
{
  __shared__ float sm[NC][64 + 1];
  int b   = blockIdx.x;
  int xb  = b & 7;
  int y   = (b >> 3) & 511;
  int p   = b >> 12;
  int x0  = xb << 6;
  int tid = threadIdx.x;
#pragma unroll
  for (int k = 0; k < 4; ++k) {
    int e = tid + k * 256;
    int c = e >> 6, x = e & 63;
    sm[c][x] = nt_loadf(&in[(size_t)((p * NC + c) * RES + y) * RES + x0 + x]);
  }
  __syncthreads();
#pragma unroll
  for (int k = 0; k < 4; ++k) {
    int e = tid + k * 256;
    int x = e >> 4, c = e & 15;
    out[(size_t)((p * RES + y) * RES + x0 + x) * NC + c] = __float2bfloat16(sm[c][x]);
  }
}

__global__ void transpose_lines_k(const float* __restrict__ in, float* __restrict__ out)
{
  int i = blockIdx.x * 256 + threadIdx.x;
  if (i >= NPLANES * RES * NC) return;
  int c = i & 15;
  int l = (i >> 4) & 511;
  int p = i >> 13;
  out[i] = nt_loadf(&in[(p * NC + c) * RES + l]);
}

// ---------------------------------------------------------------------------
// 2-stage scan (stage-3 fused into scatter).
// ---------------------------------------------------------------------------
__global__ __launch_bounds__(256) void scan1_k(
    const unsigned* __restrict__ hist, unsigned* __restrict__ offs,
    unsigned* __restrict__ bsum)
{
  __shared__ unsigned s[256];
  int b = blockIdx.x, t = threadIdx.x;
  unsigned v = hist[b * 256 + t];
  s[t] = v;
  __syncthreads();
  for (int d = 1; d < 256; d <<= 1) {
    unsigned u = (t >= d) ? s[t - d] : 0u;
    __syncthreads();
    s[t] += u;
    __syncthreads();
  }
  offs[b * 256 + t] = s[t] - v;   // exclusive within block
  if (t == 255) bsum[b] = s[255];
}

__global__ __launch_bounds__(128) void scan2_k(unsigned* __restrict__ bsum)
{
  __shared__ unsigned s[128];
  int t = threadIdx.x;
  unsigned v = bsum[t];
  s[t] = v;
  __syncthreads();
  for (int d = 1; d < 128; d <<= 1) {
    unsigned u = (t >= d) ? s[t - d] : 0u;
    __syncthreads();
    s[t] += u;
    __syncthreads();
  }
  bsum[t] = s[t] - v;   // exclusive
}

// Atomic-free scatter; global off = offs[cell] + bsum[cell>>8] (scan3 fused).
__global__ __launch_bounds__(256) void scatter_k(
    const float* __restrict__ pts, const float* __restrict__ ts,
    const unsigned* __restrict__ rank, const unsigned* __restrict__ offs,
    const unsigned* __restrict__ bsum,
    f32x4* __restrict__ rec, unsigned* __restrict__ oidx, int N)
{
  int base = (blockIdx.x * 256 + threadIdx.x) * 4;
  if (base >= N) return;
  if (base + 4 <= N) {
    uint4 rv = *(const uint4*)(rank + base);
    const f32x4* p4 = (const f32x4*)(pts + 3 * (size_t)base);
    f32x4 a = p4[0], b = p4[1], c = p4[2];
    f32x4 tv = *(const f32x4*)(ts + base);
    int c0 = cell_of(a.x, a.y, a.z);
    int c1 = cell_of(a.w, b.x, b.y);
    int c2 = cell_of(b.z, b.w, c.x);
    int c3 = cell_of(c.y, c.z, c.w);
    unsigned p0 = offs[c0] + bsum[c0 >> 8] + rv.x;
    unsigned p1 = offs[c1] + bsum[c1 >> 8] + rv.y;
    unsigned p2 = offs[c2] + bsum[c2 >> 8] + rv.z;
    unsigned p3 = offs[c3] + bsum[c3 >> 8] + rv.w;
    f32x4 r0; r0.x = a.x; r0.y = a.y; r0.z = a.z; r0.w = tv.x;
    f32x4 r1; r1.x = a.w; r1.y = b.x; r1.z = b.y; r1.w = tv.y;
    f32x4 r2; r2.x = b.z; r2.y = b.w; r2.z = c.x; r2.w = tv.z;
    f32x4 r3; r3.x = c.y; r3.y = c.z; r3.z = c.w; r3.w = tv.w;
    rec[p0] = r0; rec[p1] = r1; rec[p2] = r2; rec[p3] = r3;
    oidx[p0] = base + 0; oidx[p1] = base + 1;
    oidx[p2] = base + 2; oidx[p3] = base + 3;
  } else {
    for (int j = 0; j < 4 && base + j < N; ++j) {
      int i = base + j;
      int cc = cell_of(pts[3 * i], pts[3 * i + 1], pts[3 * i + 2]);
      unsigned pos = offs[cc] + bsum[cc >> 8] + rank[i];
      f32x4 r; r.x = pts[3 * i]; r.y = pts[3 * i + 1]; r.z = pts[3 * i + 2];
      r.w = ts[i];
      rec[pos] = r;
      oidx[pos] = i;
    }
  }
}

// ---------------------------------------------------------------------------
// Sorted main kernel (R14 form, unchanged). rec/oidx coalesced; batched
// per-plane gathers; two 16-output phases, wave-coop full-64B-line stores.
// ---------------------------------------------------------------------------
__global__ __launch_bounds__(256) void visnerf_sorted_k(
    const f32x4* __restrict__ rec, const unsigned* __restrict__ oidx,
    const __hip_bfloat16* __restrict__ planesb, const float* __restrict__ lines,
    const float* __restrict__ pg, const float* __restrict__ W,
    float* __restrict__ out, int N)
{
  __shared__ __align__(16) float sW[32 * 20];
  __shared__ __align__(16) float st[256 * 16];
  __shared__ float spg[9];
  int tid = threadIdx.x;
  for (int e = tid; e < 640; e += 256) {
    int o = e / 20, c = e - o * 20;
    sW[e] = (c < 19) ? W[o * 19 + c] : 0.0f;
  }
  if (tid < 9) spg[tid] = pg[tid];
  __syncthreads();

  int nwg = gridDim.x, bid = blockIdx.x;
  int sbid = ((nwg & 7) == 0) ? ((bid & 7) * (nwg >> 3) + (bid >> 3)) : bid;
  int j  = sbid * 256 + tid;
  int jc = (j < N) ? j : (N - 1);

  f32x4 r = nt_load4((const float*)(rec + jc));
  unsigned oi = nt_loadu(oidx + jc);
  float t = r.w;

  float nn[3];
  nn[0] = (r.x - 1.3f) * NORM_K - 1.0f;
  nn[1] = (r.y - 1.3f) * NORM_K - 1.0f;
  nn[2] = (r.z - 1.3f) * NORM_K - 1.0f;

  float feats[20];
#pragma unroll
  for (int c = 0; c < 20; ++c) feats[c] = 0.0f;

  const int matx[3] = {0, 0, 1};
  const int maty[3] = {1, 2, 2};
  const int vecm[3] = {2, 1, 0};

#pragma unroll
  for (int q = 0; q < 3; ++q) {
    float x  = nn[matx[q]], y = nn[maty[q]], lc = nn[vecm[q]];
    float ix = (x + 1.0f) * 0.5f * (float)(RES - 1);
    float iy = (y + 1.0f) * 0.5f * (float)(RES - 1);
    float fx = floorf(ix), fy = floorf(iy);
    float wx = ix - fx, wy = iy - fy;
    int x0 = (int)fx; x0 = x0 < 0 ? 0 : (x0 > RES - 1 ? RES - 1 : x0);
    int y0 = (int)fy; y0 = y0 < 0 ? 0 : (y0 > RES - 1 ? RES - 1 : y0);
    int x1 = (x0 + 1 > RES - 1) ? RES - 1 : x0 + 1;
    int y1 = (y0 + 1 > RES - 1) ? RES - 1 : y0 + 1;

    float il = (lc + 1.0f) * 0.5f * (float)(RES - 1);
    float fl = floorf(il);
    float wl = il - fl;
    int l0 = (int)fl; l0 = l0 < 0 ? 0 : (l0 > RES - 1 ? RES - 1 : l0);
    int l1 = (l0 + 1 > RES - 1) ? RES - 1 : l0 + 1;

    float w00 = (1.0f - wy) * (1.0f - wx);
    float w01 = (1.0f - wy) * wx;
    float w10 = wy * (1.0f - wx);
    float w11 = wy * wx;
    float wl0 = 1.0f - wl;

    const uint4* ta = (const uint4*)(planesb + (size_t)((q * RES + y0) * RES + x0) * NC);
    const uint4* tb = (const uint4*)(planesb + (size_t)((q * RES + y0) * RES + x1) * NC);
    const uint4* tc = (const uint4*)(planesb + (size_t)((q * RES + y1) * RES + x0) * NC);
    const uint4* td = (const uint4*)(planesb + (size_t)((q * RES + y1) * RES + x1) * NC);
    const float4* L0 = (const float4*)(lines + (size_t)(q * RES + l0) * NC);
    const float4* L1 = (const float4*)(lines + (size_t)(q * RES + l1) * NC);

    uint4 A0 = ta[0], A1 = ta[1];
    uint4 B0 = tb[0], B1 = tb[1];
    uint4 C0 = tc[0], C1 = tc[1];
    uint4 D0 = td[0], D1 = td[1];
    float4 E00 = L0[0], E01 = L0[1], E02 = L0[2], E03 = L0[3];
    float4 E10 = L1[0], E11 = L1[1], E12 = L1[2], E13 = L1[3];

    unsigned pa[8] = {A0.x, A0.y, A0.z, A0.w, A1.x, A1.y, A1.z, A1.w};
    unsigned pb[8] = {B0.x, B0.y, B0.z, B0.w, B1.x, B1.y, B1.z, B1.w};
    unsigned pc[8] = {C0.x, C0.y, C0.z, C0.w, C1.x, C1.y, C1.z, C1.w};
    unsigned pd[8] = {D0.x, D0.y, D0.z, D0.w, D1.x, D1.y, D1.z, D1.w};
    float l0v[16] = {E00.x, E00.y, E00.z, E00.w, E01.x, E01.y, E01.z, E01.w,
                     E02.x, E02.y, E02.z, E02.w, E03.x, E03.y, E03.z, E03.w};
    float l1v[16] = {E10.x, E10.y, E10.z, E10.w, E11.x, E11.y, E11.z, E11.w,
                     E12.x, E12.y, E12.z, E12.w, E13.x, E13.y, E13.z, E13.w};

#pragma unroll
    for (int w = 0; w < 8; ++w) {
      int c0 = 2 * w;
      float pf0 = w00 * bf_lo(pa[w]) + w01 * bf_lo(pb[w]) +
                  w10 * bf_lo(pc[w]) + w11 * bf_lo(pd[w]);
      float pf1 = w00 * bf_hi(pa[w]) + w01 * bf_hi(pb[w]) +
                  w10 * bf_hi(pc[w]) + w11 * bf_hi(pd[w]);
      float lf0 = wl0 * l0v[2 * w]     + wl * l1v[2 * w];
      float lf1 = wl0 * l0v[2 * w + 1] + wl * l1v[2 * w + 1];
      feats[c0 + 0] += pf0 * lf0;
      feats[c0 + 1] += pf1 * lf1;
    }
  }

  {
    float it = (t + 1.0f) * 0.5f * 2.0f;
    float ft = floorf(it);
    float wt = it - ft;
    int t0 = (int)ft; t0 = t0 < 0 ? 0 : (t0 > 2 ? 2 : t0);
    int t1 = (t0 + 1 > 2) ? 2 : t0 + 1;
    feats[16] = spg[0 + t0] * (1.0f - wt) + spg[0 + t1] * wt;
    feats[17] = spg[3 + t0] * (1.0f - wt) + spg[3 + t1] * wt;
    feats[18] = spg[6 + t0] * (1.0f - wt) + spg[6 + t1] * wt;
    feats[19] = 0.0f;
  }

  int lane  = tid & 63;
  int wbase = tid & ~63;
  int chunk = lane & 3;
  int psel  = lane >> 2;
#pragma unroll
  for (int ph = 0; ph < 2; ++ph) {
#pragma unroll
    for (int o = 0; o < 16; ++o) {
      int oo = ph * 16 + o;
      const float4* wr = (const float4*)(sW + oo * 20);
      float acc = 0.0f;
#pragma unroll
      for (int k = 0; k < 5; ++k) {
        float4 wv = wr[k];
        acc += feats[4 * k + 0] * wv.x + feats[4 * k + 1] * wv.y +
               feats[4 * k + 2] * wv.z + feats[4 * k + 3] * wv.w;
      }
      st[tid * 16 + ((o + (tid >> 1)) & 15)] = acc;
    }
#pragma unroll
    for (int g = 0; g < 4; ++g) {
      int owner_lane = g * 16 + psel;
      int pt = wbase + owner_lane;
      int jp = sbid * 256 + pt;
      unsigned oi_p = (unsigned)__shfl((int)oi, owner_lane, 64);
      f32x4 v;
#pragma unroll
      for (int jj = 0; jj < 4; ++jj) {
        int o = chunk * 4 + jj;
        v[jj] = st[pt * 16 + ((o + (pt >> 1)) & 15)];
      }
      if (jp < N) nt_store4(out + (size_t)oi_p * 32 + ph * 16 + chunk * 4, v);
    }
  }
}

// ---------------------------------------------------------------------------
// R6 fallback main kernel (unsorted), for small-ws case.
// ---------------------------------------------------------------------------
template <bool TP>
__global__ __launch_bounds__(256) void visnerf_main_k(
    const float* __restrict__ pts, const float* __restrict__ ts,
    const __hip_bfloat16* __restrict__ planesb, const float* __restrict__ lines,
    const float* __restrict__ planes_f32, const float* __restrict__ lines_f32,
    const float* __restrict__ pg, const float* __restrict__ W,
    float* __restrict__ out, int N)
{
  __shared__ __align__(16) float sW[32 * 20];
  __shared__ __align__(16) float st[256 * 32];
  __shared__ float spg[9];
  int tid = threadIdx.x;
  for (int e = tid; e < 640; e += 256) {
    int o = e / 20, c = e - o * 20;
    sW[e] = (c < 19) ? W[o * 19 + c] : 0.0f;
  }
  if (tid < 9) spg[tid] = pg[tid];
  __syncthreads();

  int i  = blockIdx.x * 256 + tid;
  int ii = (i < N) ? i : (N - 1);
  float px = nt_loadf(&pts[ii * 3 + 0]);
  float py = nt_loadf(&pts[ii * 3 + 1]);
  float pz = nt_loadf(&pts[ii * 3 + 2]);
  float t  = nt_loadf(&ts[ii]);

  float nn[3];
  nn[0] = (px - 1.3f) * NORM_K - 1.0f;
  nn[1] = (py - 1.3f) * NORM_K - 1.0f;
  nn[2] = (pz - 1.3f) * NORM_K - 1.0f;

  float feats[20];
#pragma unroll
  for (int c = 0; c < 20; ++c) feats[c] = 0.0f;

  const int matx[3] = {0, 0, 1};
  const int maty[3] = {1, 2, 2};
  const int vecm[3] = {2, 1, 0};

#pragma unroll
  for (int q = 0; q < 3; ++q) {
    float x  = nn[matx[q]], y = nn[maty[q]], lc = nn[vecm[q]];
    float ix = (x + 1.0f) * 0.5f * (float)(RES - 1);
    float iy = (y + 1.0f) * 0.5f * (float)(RES - 1);
    float fx = floorf(ix), fy = floorf(iy);
    float wx = ix - fx, wy = iy - fy;
    int x0 = (int)fx; x0 = x0 < 0 ? 0 : (x0 > RES - 1 ? RES - 1 : x0);
    int y0 = (int)fy; y0 = y0 < 0 ? 0 : (y0 > RES - 1 ? RES - 1 : y0);
    int x1 = (x0 + 1 > RES - 1) ? RES - 1 : x0 + 1;
    int y1 = (y0 + 1 > RES - 1) ? RES - 1 : y0 + 1;

    float il = (lc + 1.0f) * 0.5f * (float)(RES - 1);
    float fl = floorf(il);
    float wl = il - fl;
    int l0 = (int)fl; l0 = l0 < 0 ? 0 : (l0 > RES - 1 ? RES - 1 : l0);
    int l1 = (l0 + 1 > RES - 1) ? RES - 1 : l0 + 1;

    float w00 = (1.0f - wy) * (1.0f - wx);
    float w01 = (1.0f - wy) * wx;
    float w10 = wy * (1.0f - wx);
    float w11 = wy * wx;
    float wl0 = 1.0f - wl;

    if (TP) {
      const uint4* ta = (const uint4*)(planesb + (size_t)((q * RES + y0) * RES + x0) * NC);
      const uint4* tb = (const uint4*)(planesb + (size_t)((q * RES + y0) * RES + x1) * NC);
      const uint4* tc = (const uint4*)(planesb + (size_t)((q * RES + y1) * RES + x0) * NC);
      const uint4* td = (const uint4*)(planesb + (size_t)((q * RES + y1) * RES + x1) * NC);
      const float4* L0 = (const float4*)(lines + (size_t)(q * RES + l0) * NC);
      const float4* L1 = (const float4*)(lines + (size_t)(q * RES + l1) * NC);
#pragma unroll
      for (int h = 0; h < 2; ++h) {
        uint4 ua = ta[h], ub = tb[h], uc = tc[h], ud = td[h];
        float4 e0a = L0[2 * h + 0], e0b = L0[2 * h + 1];
        float4 e1a = L1[2 * h + 0], e1b = L1[2 * h + 1];
        const unsigned* pa = &ua.x;
        const unsigned* pb = &ub.x;
        const unsigned* pc = &uc.x;
        const unsigned* pd = &ud.x;
        const float* q0 = &e0a.x;
        const float* q1 = &e1a.x;
#pragma unroll
        for (int w = 0; w < 4; ++w) {
          int c0 = h * 8 + 2 * w;
          float pf0 = w00 * bf_lo(pa[w]) + w01 * bf_lo(pb[w]) +
                      w10 * bf_lo(pc[w]) + w11 * bf_lo(pd[w]);
          float pf1 = w00 * bf_hi(pa[w]) + w01 * bf_hi(pb[w]) +
                      w10 * bf_hi(pc[w]) + w11 * bf_hi(pd[w]);
          float lf0 = (w < 2) ? (wl0 * q0[2 * w] + wl * q1[2 * w])
                              : (wl0 * (&e0b.x)[2 * w - 4] + wl * (&e1b.x)[2 * w - 4]);
          float lf1 = (w < 2) ? (wl0 * q0[2 * w + 1] + wl * q1[2 * w + 1])
                              : (wl0 * (&e0b.x)[2 * w - 3] + wl * (&e1b.x)[2 * w - 3]);
          feats[c0 + 0] += pf0 * lf0;
          feats[c0 + 1] += pf1 * lf1;
        }
      }
    } else {
#pragma unroll 4
      for (int c = 0; c < NC; ++c) {
        const float* pl = planes_f32 + (size_t)(q * NC + c) * RES * RES;
        float a  = pl[y0 * RES + x0], b = pl[y0 * RES + x1];
        float c2 = pl[y1 * RES + x0], d = pl[y1 * RES + x1];
        const float* ln = lines_f32 + (size_t)(q * NC + c) * RES;
        float lf = ln[l0] * wl0 + ln[l1] * wl;
        feats[c] += (w00 * a + w01 * b + w10 * c2 + w11 * d) * lf;
      }
    }
  }

  {
    float it = (t + 1.0f) * 0.5f * 2.0f;
    float ft = floorf(it);
    float wt = it - ft;
    int t0 = (int)ft; t0 = t0 < 0 ? 0 : (t0 > 2 ? 2 : t0);
    int t1 = (t0 + 1 > 2) ? 2 : t0 + 1;
    feats[16] = spg[0 + t0] * (1.0f - wt) + spg[0 + t1] * wt;
    feats[17] = spg[3 + t0] * (1.0f - wt) + spg[3 + t1] * wt;
    feats[18] = spg[6 + t0] * (1.0f - wt) + spg[6 + t1] * wt;
    feats[19] = 0.0f;
  }

  float res[32];
#pragma unroll
  for (int o = 0; o < 32; ++o) {
    const float4* wr = (const float4*)(sW + o * 20);
    float acc = 0.0f;
#pragma unroll
    for (int k = 0; k < 5; ++k) {
      float4 wv = wr[k];
      acc += feats[4 * k + 0] * wv.x + feats[4 * k + 1] * wv.y +
             feats[4 * k + 2] * wv.z + feats[4 * k + 3] * wv.w;
    }
    res[o] = acc;
  }

#pragma unroll
  for (int o = 0; o < 32; ++o)
    st[tid * 32 + ((o + tid) & 31)] = res[o];
  __syncthreads();

  size_t gbase = (size_t)blockIdx.x * 8192;
  size_t total = (size_t)N * 32;
#pragma unroll
  for (int k = 0; k < 8; ++k) {
    int idx = tid + k * 256;
    int j   = idx * 4;
    int pq  = j >> 5;
    f32x4 v;
    v.x = st[pq * 32 + (((j & 31) + 0 + pq) & 31)];
    v.y = st[pq * 32 + (((j & 31) + 1 + pq) & 31)];
    v.z = st[pq * 32 + (((j & 31) + 2 + pq) & 31)];
    v.w = st[pq * 32 + (((j & 31) + 3 + pq) & 31)];
    if (gbase + j + 4 <= total) {
      nt_store4(out + gbase + j, v);
    }
  }
}

extern "C" void kernel_launch(void* const* d_in, const int* in_sizes, int n_in,
                              void* d_out, int out_size, void* d_ws, size_t ws_size,
                              hipStream_t stream)
{
  const float* pts    = (const float*)d_in[0];
  const float* ts     = (const float*)d_in[1];
  const float* planes = (const float*)d_in[2];
  const float* lines  = (const float*)d_in[3];
  const float* pg     = (const float*)d_in[4];
  const float* W      = (const float*)d_in[5];
  float* out = (float*)d_out;
  int N = in_sizes[0] / 3;
  int blocksN = (N + 255) / 256;
  int blocks4 = (N + 1023) / 1024;

  auto align256 = [](size_t x) { return (x + 255) & ~(size_t)255; };
  size_t planesTb_bytes = align256((size_t)NPLANES * RES * RES * NC * 2);
  size_t linesT_bytes   = align256((size_t)NPLANES * RES * NC * 4);
  size_t hist_bytes     = align256((size_t)NCELLS * 4);
  size_t offs_bytes     = align256((size_t)NCELLS * 4);
  size_t bsum_bytes     = align256((size_t)128 * 4);
  size_t rank_bytes     = align256((size_t)N * 4);
  size_t oidx_bytes     = align256((size_t)N * 4);
  size_t rec_bytes      = align256((size_t)N * 16);
  size_t sorted_total = planesTb_bytes + linesT_bytes + hist_bytes + offs_bytes +
                        bsum_bytes + rank_bytes + oidx_bytes + rec_bytes;

  if (ws_size >= sorted_total) {
    char* p = (char*)d_ws;
    __hip_bfloat16* planesTb = (__hip_bfloat16*)p;       p += planesTb_bytes;
    float*    linesT = (float*)p;                        p += linesT_bytes;
    unsigned* hist   = (unsigned*)p;                     p += hist_bytes;
    unsigned* offs   = (unsigned*)p;                     p += offs_bytes;
    unsigned* bsum   = (unsigned*)p;                     p += bsum_bytes;
    unsigned* rank   = (unsigned*)p;                     p += rank_bytes;
    unsigned* oidx   = (unsigned*)p;                     p += oidx_bytes;
    f32x4*    rec    = (f32x4*)p;

    // zero the histogram via stream-ordered memset (graph-capture safe)
    hipMemsetAsync(hist, 0, (size_t)NCELLS * 4, stream);

    // fused: histrank (critical path, first) + line transpose + plane transpose
    int HB = blocks4;
    int fusedBlocks = HB + 96 + NPLANES * RES * (RES / 64);
    fused_pre_k<<<fusedBlocks, 256, 0, stream>>>(
        planes, planesTb, lines, linesT, pts, hist, rank, N, HB);

    scan1_k<<<NCELLS / 256, 256, 0, stream>>>(hist, offs, bsum);
    scan2_k<<<1, 128, 0, stream>>>(bsum);
    scatter_k<<<blocks4, 256, 0, stream>>>(pts, ts, rank, offs, bsum, rec, oidx, N);
    visnerf_sorted_k<<<blocksN, 256, 0, stream>>>(rec, oidx, planesTb, linesT,
                                                  pg, W, out, N);
  } else if (ws_size >= planesTb_bytes + linesT_bytes) {
    __hip_bfloat16* planesTb = (__hip_bfloat16*)d_ws;
    float* linesT = (float*)((char*)d_ws + planesTb_bytes);
    transpose_planes_k<<<NPLANES * RES * (RES / 64), 256, 0, stream>>>(planes, planesTb);
    transpose_lines_k<<<(NPLANES * RES * NC + 255) / 256, 256, 0, stream>>>(lines, linesT);
    visnerf_main_k<true><<<blocksN, 256, 0, stream>>>(
        pts, ts, planesTb, linesT, nullptr, nullptr, pg, W, out, N);
  } else {
    visnerf_main_k<false><<<blocksN, 256, 0, stream>>>(
        pts, ts, nullptr, nullptr, planes, lines, pg, W, out, N);
  }
}